// Round 5
// baseline (407.823 us; speedup 1.0000x reference)
//
#include <hip/hip_runtime.h>
#include <math.h>

// B=4, L=2048, D=1024, H=16, dh=64, M=8192, scale=0.125
// All-plain-bf16 MFMA pipeline; fp32->bf16 A-convert fused into GEMM staging.
// grid(64,8) x=m-block: linear id % 8 == m-block % 8 -> same-A blocks share XCD L2.

using f32x4 = __attribute__((ext_vector_type(4))) float;
using bf16x8 = __attribute__((ext_vector_type(8))) short;

__device__ __forceinline__ unsigned short f2bf(float x) {
  union { float f; unsigned u; } v; v.f = x;
  unsigned r = v.u + 0x7fff + ((v.u >> 16) & 1);  // RNE
  return (unsigned short)(r >> 16);
}

__device__ __forceinline__ void g2l16(const void* g, void* l) {
  __builtin_amdgcn_global_load_lds(
      (const __attribute__((address_space(1))) unsigned int*)g,
      (__attribute__((address_space(3))) unsigned int*)l, 16, 0, 0);
}

// Transpose weights: W[1024 k][1024 n] fp32 -> WT[n][k] bf16
__global__ __launch_bounds__(256) void wt_k(const float* __restrict__ W,
                                            short* __restrict__ hiT) {
  __shared__ float t[64][65];
  const int n0 = blockIdx.x * 64, k0 = blockIdx.y * 64;
  const int tid = threadIdx.x;
  const int r = tid >> 4, c4 = (tid & 15) * 4;
#pragma unroll
  for (int i = 0; i < 4; i++) {
    const int row = r + i * 16;  // k
    const float4 v = *(const float4*)&W[(size_t)(k0 + row) * 1024 + n0 + c4];
    t[c4 + 0][row] = v.x;
    t[c4 + 1][row] = v.y;
    t[c4 + 2][row] = v.z;
    t[c4 + 3][row] = v.w;
  }
  __syncthreads();
#pragma unroll
  for (int i = 0; i < 4; i++) {
    const int row = r + i * 16;  // n
    short4 h;
    h.x = (short)f2bf(t[row][c4 + 0]);
    h.y = (short)f2bf(t[row][c4 + 1]);
    h.z = (short)f2bf(t[row][c4 + 2]);
    h.w = (short)f2bf(t[row][c4 + 3]);
    *(short4*)&hiT[(size_t)(n0 + row) * 1024 + k0 + c4] = h;
  }
}

// MFMA GEMM: C[8192,1024] = A @ WT^T + bias. 128x128 tile, BK=32.
// AFP32: A is fp32, converted to bf16 during staging (register-prefetch).
// EPI: 0=Q(x0.125, bf16 BHLd) 1=K(bf16 BHLd) 2=V(bf16 [B,H,64,L], LDS-bounce)
//      3=fp32 flat
template <int AFP32, int EPI>
__global__ __launch_bounds__(256, 2) void gemm_mfma_k(
    const void* __restrict__ A_g, const short* __restrict__ B_g,
    const float* __restrict__ bias, void* __restrict__ out0) {
  __shared__ short smem[64 * 144];  // As[0..4096) Bs[4096..8192); EPI2 reuses as T
  short* As = smem;
  short* Bs = smem + 4096;

  const int tid = threadIdx.x;
  const int lane = tid & 63;
  const int wave = tid >> 6;
  const int quad = lane >> 4;
  const int l16 = lane & 15;
  const int m0 = blockIdx.x * 128;  // m on x: same-A blocks on same XCD
  const int n0 = blockIdx.y * 128;
  const int wm = (wave >> 1) * 64;
  const int wn = (wave & 1) * 64;

  const int srow = tid >> 2;       // B staging (g2l16 lane-linear)
  const int soff = (tid & 3) * 8;
  const int arow = tid >> 1;       // A fp32 staging: 128 rows, 16 floats/thread
  const int acol = (tid & 1) * 16;

  f32x4 acc[4][4];
#pragma unroll
  for (int i = 0; i < 4; i++)
#pragma unroll
    for (int j = 0; j < 4; j++) acc[i][j] = f32x4{0.f, 0.f, 0.f, 0.f};

  float4 apre[4];
  if (AFP32) {
    const float* Af = (const float*)A_g;
#pragma unroll
    for (int j = 0; j < 4; j++)
      apre[j] = *(const float4*)&Af[(size_t)(m0 + arow) * 1024 + acol + j * 4];
  }

  for (int k0 = 0; k0 < 1024; k0 += 32) {
    __syncthreads();  // prev iter's LDS reads done
    if (AFP32) {
      short tmp[16];
      const float af[16] = {apre[0].x, apre[0].y, apre[0].z, apre[0].w,
                            apre[1].x, apre[1].y, apre[1].z, apre[1].w,
                            apre[2].x, apre[2].y, apre[2].z, apre[2].w,
                            apre[3].x, apre[3].y, apre[3].z, apre[3].w};
#pragma unroll
      for (int j = 0; j < 16; j++) tmp[j] = (short)f2bf(af[j]);
      *(bf16x8*)&As[arow * 32 + acol] = *(const bf16x8*)&tmp[0];
      *(bf16x8*)&As[arow * 32 + acol + 8] = *(const bf16x8*)&tmp[8];
    } else {
#pragma unroll
      for (int i = 0; i < 2; i++) {
        const int row = srow + i * 64;
        g2l16(&((const short*)A_g)[(size_t)(m0 + row) * 1024 + k0 + soff],
              &As[row * 32 + soff]);
      }
    }
#pragma unroll
    for (int i = 0; i < 2; i++) {
      const int row = srow + i * 64;
      g2l16(&B_g[(size_t)(n0 + row) * 1024 + k0 + soff], &Bs[row * 32 + soff]);
    }
    __syncthreads();  // barrier drains vmcnt+lgkmcnt -> LDS ready

    if (AFP32 && k0 < 992) {  // prefetch next A tile; overlaps MFMA below
      const float* Af = (const float*)A_g;
#pragma unroll
      for (int j = 0; j < 4; j++)
        apre[j] = *(const float4*)&Af[(size_t)(m0 + arow) * 1024 + k0 + 32 + acol + j * 4];
    }

    bf16x8 ah[4], bh[4];
#pragma unroll
    for (int t = 0; t < 4; t++) {
      ah[t] = *(const bf16x8*)&As[(wm + t * 16 + l16) * 32 + quad * 8];
      bh[t] = *(const bf16x8*)&Bs[(wn + t * 16 + l16) * 32 + quad * 8];
    }
#pragma unroll
    for (int tm = 0; tm < 4; tm++)
#pragma unroll
      for (int tn = 0; tn < 4; tn++)
        acc[tm][tn] = __builtin_amdgcn_mfma_f32_16x16x32_bf16(ah[tm], bh[tn], acc[tm][tn], 0, 0, 0);
  }

  float bz[4];
#pragma unroll
  for (int tn = 0; tn < 4; tn++) bz[tn] = bias[n0 + wn + tn * 16 + l16];

  if (EPI == 2) {
    // V: [B,H,64,L] via LDS transpose (pad 144 shorts/row), coalesced b128 out
    const int b = m0 >> 11;
    const int lbase = m0 & 2047;
#pragma unroll
    for (int half = 0; half < 2; half++) {
      __syncthreads();
      if ((wave & 1) == half) {
#pragma unroll
        for (int tm = 0; tm < 4; tm++)
#pragma unroll
          for (int tn = 0; tn < 4; tn++)
#pragma unroll
            for (int r = 0; r < 4; r++) {
              const int nl = tn * 16 + l16;                // 0..63 (d)
              const int ml = wm + tm * 16 + quad * 4 + r;  // 0..127 (l)
              smem[nl * 144 + ml] = (short)f2bf(acc[tm][tn][r] + bz[tn]);
            }
      }
      __syncthreads();
      const int h = (n0 >> 6) + half;
#pragma unroll
      for (int j = 0; j < 4; j++) {
        const int c = tid + j * 256;
        const int d = c >> 4;
        const int mo = (c & 15) * 8;
        *(bf16x8*)&((short*)out0)[((size_t)((b * 16 + h) * 64 + d)) * 2048 + lbase + mo] =
            *(const bf16x8*)&smem[d * 144 + mo];
      }
    }
    return;
  }

#pragma unroll
  for (int tm = 0; tm < 4; tm++) {
#pragma unroll
    for (int tn = 0; tn < 4; tn++) {
      const int n = n0 + wn + tn * 16 + l16;
#pragma unroll
      for (int r = 0; r < 4; r++) {
        const int m = m0 + wm + tm * 16 + quad * 4 + r;
        const float val = acc[tm][tn][r] + bz[tn];
        const int b = m >> 11, lrow = m & 2047;
        const int h = n >> 6, d = n & 63;
        if (EPI == 0) {
          ((short*)out0)[((size_t)(b * 16 + h) * 2048 + lrow) * 64 + d] =
              (short)f2bf(val * 0.125f);
        } else if (EPI == 1) {
          ((short*)out0)[((size_t)(b * 16 + h) * 2048 + lrow) * 64 + d] =
              (short)f2bf(val);
        } else {
          ((float*)out0)[(size_t)m * 1024 + n] = val;
        }
      }
    }
  }
}

// Flash attention, all-plain bf16, no max-tracking (scores small; softmax
// shift-invariant). Block = (b,h) x 128 Q rows; 4 waves x 32 rows.
// l via ones-vector MFMA. P stored TRUNCATED to bf16 (bias cancels in l,
// which is computed from the same truncated P).
__global__ __launch_bounds__(256, 4) void attn3_k(const short* __restrict__ Qp,
                                                  const short* __restrict__ Kp,
                                                  const short* __restrict__ Vt,
                                                  short* __restrict__ Ctx) {
  __shared__ short Ks[64 * 72];   // [key][d]
  __shared__ short Vs[64 * 72];   // [d][key]
  __shared__ short Ps[128 * 72];  // [qrow][key]

  const int tid = threadIdx.x;
  const int lane = tid & 63;
  const int wave = tid >> 6;
  const int quad = lane >> 4;
  const int l16 = lane & 15;
  const int bh = blockIdx.y;
  const int q0 = blockIdx.x * 128;

  const short* Kb = Kp + (size_t)bh * 2048 * 64;
  const short* Vb = Vt + (size_t)bh * 64 * 2048;

  bf16x8 qf[2][2];
#pragma unroll
  for (int s = 0; s < 2; s++) {
    const short* qp =
        Qp + ((size_t)bh * 2048 + q0 + wave * 32 + s * 16 + l16) * 64 + quad * 8;
    qf[s][0] = *(const bf16x8*)qp;
    qf[s][1] = *(const bf16x8*)(qp + 32);
  }

  bf16x8 ones;
#pragma unroll
  for (int j = 0; j < 8; j++) ones[j] = (short)0x3F80;

  f32x4 O[2][4], lacc[2];
#pragma unroll
  for (int s = 0; s < 2; s++) {
    lacc[s] = f32x4{0.f, 0.f, 0.f, 0.f};
#pragma unroll
    for (int jo = 0; jo < 4; jo++) O[s][jo] = f32x4{0.f, 0.f, 0.f, 0.f};
  }

  const int srow0 = tid >> 3, soff = (tid & 7) * 8;
  const int srow1 = (tid + 256) >> 3;

  bf16x8 kreg[2], vreg[2];
  kreg[0] = *(const bf16x8*)&Kb[(size_t)srow0 * 64 + soff];
  kreg[1] = *(const bf16x8*)&Kb[(size_t)srow1 * 64 + soff];
  vreg[0] = *(const bf16x8*)&Vb[(size_t)srow0 * 2048 + soff];
  vreg[1] = *(const bf16x8*)&Vb[(size_t)srow1 * 2048 + soff];

  for (int kt = 0; kt < 32; kt++) {
    __syncthreads();
    *(bf16x8*)&Ks[srow0 * 72 + soff] = kreg[0];
    *(bf16x8*)&Ks[srow1 * 72 + soff] = kreg[1];
    *(bf16x8*)&Vs[srow0 * 72 + soff] = vreg[0];
    *(bf16x8*)&Vs[srow1 * 72 + soff] = vreg[1];
    __syncthreads();

    if (kt < 31) {
      const int nb = (kt + 1) * 64;
      kreg[0] = *(const bf16x8*)&Kb[(size_t)(nb + srow0) * 64 + soff];
      kreg[1] = *(const bf16x8*)&Kb[(size_t)(nb + srow1) * 64 + soff];
      vreg[0] = *(const bf16x8*)&Vb[(size_t)srow0 * 2048 + nb + soff];
      vreg[1] = *(const bf16x8*)&Vb[(size_t)srow1 * 2048 + nb + soff];
    }

#pragma unroll
    for (int s = 0; s < 2; s++) {
      f32x4 sacc[4];
#pragma unroll
      for (int j = 0; j < 4; j++) sacc[j] = f32x4{0.f, 0.f, 0.f, 0.f};
#pragma unroll
      for (int c = 0; c < 2; c++)
#pragma unroll
        for (int j = 0; j < 4; j++) {
          const bf16x8 kf = *(const bf16x8*)&Ks[(j * 16 + l16) * 72 + c * 32 + quad * 8];
          sacc[j] = __builtin_amdgcn_mfma_f32_16x16x32_bf16(qf[s][c], kf, sacc[j], 0, 0, 0);
        }
#pragma unroll
      for (int j = 0; j < 4; j++)
#pragma unroll
        for (int r = 0; r < 4; r++) {
          const float e = __expf(sacc[j][r]);
          Ps[(wave * 32 + s * 16 + quad * 4 + r) * 72 + j * 16 + l16] =
              (short)(__float_as_uint(e) >> 16);  // truncation: bias cancels in l
        }
    }
    // no barrier: P readback is wave-local

#pragma unroll
    for (int c = 0; c < 2; c++) {
      const bf16x8 pf0 = *(const bf16x8*)&Ps[(wave * 32 + l16) * 72 + c * 32 + quad * 8];
      const bf16x8 pf1 = *(const bf16x8*)&Ps[(wave * 32 + 16 + l16) * 72 + c * 32 + quad * 8];
      lacc[0] = __builtin_amdgcn_mfma_f32_16x16x32_bf16(pf0, ones, lacc[0], 0, 0, 0);
      lacc[1] = __builtin_amdgcn_mfma_f32_16x16x32_bf16(pf1, ones, lacc[1], 0, 0, 0);
#pragma unroll
      for (int jo = 0; jo < 4; jo++) {
        const bf16x8 vf = *(const bf16x8*)&Vs[(jo * 16 + l16) * 72 + c * 32 + quad * 8];
        O[0][jo] = __builtin_amdgcn_mfma_f32_16x16x32_bf16(pf0, vf, O[0][jo], 0, 0, 0);
        O[1][jo] = __builtin_amdgcn_mfma_f32_16x16x32_bf16(pf1, vf, O[1][jo], 0, 0, 0);
      }
    }
  }

  const int b = bh >> 4, h = bh & 15;
#pragma unroll
  for (int s = 0; s < 2; s++)
#pragma unroll
    for (int r = 0; r < 4; r++) {
      const float inv_l = 1.0f / lacc[s][r];
      const size_t row = (size_t)b * 2048 + q0 + wave * 32 + s * 16 + quad * 4 + r;
#pragma unroll
      for (int jo = 0; jo < 4; jo++)
        Ctx[row * 1024 + h * 64 + jo * 16 + l16] = (short)f2bf(O[s][jo][r] * inv_l);
    }
}

// ===========================================================================
extern "C" void kernel_launch(void* const* d_in, const int* in_sizes, int n_in,
                              void* d_out, int out_size, void* d_ws, size_t ws_size,
                              hipStream_t stream) {
  const float* queries = (const float*)d_in[0];
  const float* keys    = (const float*)d_in[1];
  const float* values  = (const float*)d_in[2];
  const float* Wq = (const float*)d_in[3];
  const float* bq = (const float*)d_in[4];
  const float* Wk = (const float*)d_in[5];
  const float* bk = (const float*)d_in[6];
  const float* Wv = (const float*)d_in[7];
  const float* bv = (const float*)d_in[8];
  const float* Wo = (const float*)d_in[9];
  const float* bo = (const float*)d_in[10];
  float* out = (float*)d_out;

  const size_t PLANE = (size_t)8192 * 1024 * 2;
  const size_t WPL = (size_t)1024 * 1024 * 2;

  char* p = (char*)d_ws;
  short* WqT = (short*)p;  p += WPL;
  short* WkT = (short*)p;  p += WPL;
  short* WvT = (short*)p;  p += WPL;
  short* WoT = (short*)p;  p += WPL;
  short* Qp  = (short*)p;  p += PLANE;
  short* Kp  = (short*)p;  p += PLANE;
  short* Vt  = (short*)p;  p += PLANE;
  short* ctx = (short*)p;  p += PLANE;  // 75.5 MB total

  const dim3 blk(256);
  const dim3 wgrid(16, 16);
  wt_k<<<wgrid, blk, 0, stream>>>(Wq, WqT);
  wt_k<<<wgrid, blk, 0, stream>>>(Wk, WkT);
  wt_k<<<wgrid, blk, 0, stream>>>(Wv, WvT);
  wt_k<<<wgrid, blk, 0, stream>>>(Wo, WoT);

  const dim3 ggrid(64, 8);  // x = m-block (XCD-local A reuse), y = n-block

  gemm_mfma_k<1, 0><<<ggrid, blk, 0, stream>>>(queries, WqT, bq, Qp);
  gemm_mfma_k<1, 1><<<ggrid, blk, 0, stream>>>(keys,    WkT, bk, Kp);
  gemm_mfma_k<1, 2><<<ggrid, blk, 0, stream>>>(values,  WvT, bv, Vt);

  attn3_k<<<dim3(16, 64), blk, 0, stream>>>(Qp, Kp, Vt, ctx);

  gemm_mfma_k<0, 3><<<ggrid, blk, 0, stream>>>(ctx, WoT, bo, out);
}

// Round 6
// 395.875 us; speedup vs baseline: 1.0302x; 1.0302x over previous
//
#include <hip/hip_runtime.h>
#include <math.h>

// B=4, L=2048, D=1024, H=16, dh=64, M=8192, scale=0.125
// All-plain-bf16 MFMA pipeline. R6: z-batched projection GEMMs (1536 blocks
// -> 4+ blocks/CU co-residency), attn bh-major grid (XCD-local K/V), LDS-bounce
// epilogues everywhere.

using f32x4 = __attribute__((ext_vector_type(4))) float;
using bf16x8 = __attribute__((ext_vector_type(8))) short;

__device__ __forceinline__ unsigned short f2bf(float x) {
  union { float f; unsigned u; } v; v.f = x;
  unsigned r = v.u + 0x7fff + ((v.u >> 16) & 1);  // RNE
  return (unsigned short)(r >> 16);
}

__device__ __forceinline__ void g2l16(const void* g, void* l) {
  __builtin_amdgcn_global_load_lds(
      (const __attribute__((address_space(1))) unsigned int*)g,
      (__attribute__((address_space(3))) unsigned int*)l, 16, 0, 0);
}

// Transpose 4 weights in one launch: W[1024 k][1024 n] fp32 -> WT[n][k] bf16
__global__ __launch_bounds__(256) void wt4_k(const float* __restrict__ W0,
                                             const float* __restrict__ W1,
                                             const float* __restrict__ W2,
                                             const float* __restrict__ W3,
                                             short* __restrict__ WT) {
  __shared__ float t[64][65];
  const int z = blockIdx.z;
  const float* W = z == 0 ? W0 : (z == 1 ? W1 : (z == 2 ? W2 : W3));
  short* hiT = WT + (size_t)z * 1048576;
  const int n0 = blockIdx.x * 64, k0 = blockIdx.y * 64;
  const int tid = threadIdx.x;
  const int r = tid >> 4, c4 = (tid & 15) * 4;
#pragma unroll
  for (int i = 0; i < 4; i++) {
    const int row = r + i * 16;  // k
    const float4 v = *(const float4*)&W[(size_t)(k0 + row) * 1024 + n0 + c4];
    t[c4 + 0][row] = v.x;
    t[c4 + 1][row] = v.y;
    t[c4 + 2][row] = v.z;
    t[c4 + 3][row] = v.w;
  }
  __syncthreads();
#pragma unroll
  for (int i = 0; i < 4; i++) {
    const int row = r + i * 16;  // n
    short4 h;
    h.x = (short)f2bf(t[row][c4 + 0]);
    h.y = (short)f2bf(t[row][c4 + 1]);
    h.z = (short)f2bf(t[row][c4 + 2]);
    h.w = (short)f2bf(t[row][c4 + 3]);
    *(short4*)&hiT[(size_t)(n0 + row) * 1024 + k0 + c4] = h;
  }
}

// z-batched projection GEMM: for z in {0,1,2}: C_z = X_z @ WT_z^T + b_z.
// A fp32 (converted during staging). 128x128 tile, BK=32, 16 MFMA/iter.
// z=0: Q (x0.125, bf16 BHLd)  z=1: K (bf16 BHLd)  z=2: V (bf16 [B,H,64,L]).
// All epilogues LDS-bounce -> b128 coalesced stores.
__global__ __launch_bounds__(256, 4) void proj3_k(
    const float* __restrict__ A0, const float* __restrict__ A1,
    const float* __restrict__ A2, const short* __restrict__ WT,
    const float* __restrict__ b0, const float* __restrict__ b1,
    const float* __restrict__ b2, short* __restrict__ Obase) {
  __shared__ short smem[64 * 144];  // As[0..4096) Bs[4096..8192); epi reuse
  short* As = smem;
  short* Bs = smem + 4096;

  const int z = blockIdx.z;
  const float* A = z == 0 ? A0 : (z == 1 ? A1 : A2);
  const short* B_g = WT + (size_t)z * 1048576;
  const float* bias = z == 0 ? b0 : (z == 1 ? b1 : b2);
  short* outp = Obase + (size_t)z * 8388608;

  const int tid = threadIdx.x;
  const int lane = tid & 63;
  const int wave = tid >> 6;
  const int quad = lane >> 4;
  const int l16 = lane & 15;
  const int m0 = blockIdx.x * 128;  // x = m-block: same-A blocks share an XCD
  const int n0 = blockIdx.y * 128;
  const int wm = (wave >> 1) * 64;
  const int wn = (wave & 1) * 64;

  const int srow = tid >> 2;      // B staging (g2l16)
  const int soff = (tid & 3) * 8;
  const int arow = tid >> 1;      // A staging: 128 rows, 16 fp32/thread
  const int acol = (tid & 1) * 16;

  f32x4 acc[4][4];
#pragma unroll
  for (int i = 0; i < 4; i++)
#pragma unroll
    for (int j = 0; j < 4; j++) acc[i][j] = f32x4{0.f, 0.f, 0.f, 0.f};

  float4 apre[4];
#pragma unroll
  for (int j = 0; j < 4; j++)
    apre[j] = *(const float4*)&A[(size_t)(m0 + arow) * 1024 + acol + j * 4];

  for (int k0 = 0; k0 < 1024; k0 += 32) {
    __syncthreads();
    {
      short tmp[16];
      const float af[16] = {apre[0].x, apre[0].y, apre[0].z, apre[0].w,
                            apre[1].x, apre[1].y, apre[1].z, apre[1].w,
                            apre[2].x, apre[2].y, apre[2].z, apre[2].w,
                            apre[3].x, apre[3].y, apre[3].z, apre[3].w};
#pragma unroll
      for (int j = 0; j < 16; j++) tmp[j] = (short)f2bf(af[j]);
      *(bf16x8*)&As[arow * 32 + acol] = *(const bf16x8*)&tmp[0];
      *(bf16x8*)&As[arow * 32 + acol + 8] = *(const bf16x8*)&tmp[8];
    }
#pragma unroll
    for (int i = 0; i < 2; i++) {
      const int row = srow + i * 64;
      g2l16(&B_g[(size_t)(n0 + row) * 1024 + k0 + soff], &Bs[row * 32 + soff]);
    }
    __syncthreads();

    if (k0 < 992) {  // prefetch next A tile (overlaps MFMA)
#pragma unroll
      for (int j = 0; j < 4; j++)
        apre[j] = *(const float4*)&A[(size_t)(m0 + arow) * 1024 + k0 + 32 + acol + j * 4];
    }

    bf16x8 ah[4], bh[4];
#pragma unroll
    for (int t = 0; t < 4; t++) {
      ah[t] = *(const bf16x8*)&As[(wm + t * 16 + l16) * 32 + quad * 8];
      bh[t] = *(const bf16x8*)&Bs[(wn + t * 16 + l16) * 32 + quad * 8];
    }
#pragma unroll
    for (int tm = 0; tm < 4; tm++)
#pragma unroll
      for (int tn = 0; tn < 4; tn++)
        acc[tm][tn] = __builtin_amdgcn_mfma_f32_16x16x32_bf16(ah[tm], bh[tn], acc[tm][tn], 0, 0, 0);
  }

  float bz[4];
#pragma unroll
  for (int tn = 0; tn < 4; tn++) bz[tn] = bias[n0 + wn + tn * 16 + l16];
  const float sc = (z == 0) ? 0.125f : 1.0f;

  const int b = m0 >> 11;
  const int lbase = m0 & 2047;

  if (z == 2) {
    // V: [B,H,64,L] via LDS transpose (pad 144), b128 stores along L
#pragma unroll
    for (int half = 0; half < 2; half++) {
      __syncthreads();
      if ((wave & 1) == half) {
#pragma unroll
        for (int tm = 0; tm < 4; tm++)
#pragma unroll
          for (int tn = 0; tn < 4; tn++)
#pragma unroll
            for (int r = 0; r < 4; r++) {
              const int nl = tn * 16 + l16;                // d 0..63
              const int ml = wm + tm * 16 + quad * 4 + r;  // l 0..127
              smem[nl * 144 + ml] = (short)f2bf(acc[tm][tn][r] + bz[tn]);
            }
      }
      __syncthreads();
      const int h = (n0 >> 6) + half;
#pragma unroll
      for (int j = 0; j < 4; j++) {
        const int c = tid + j * 256;
        const int d = c >> 4;
        const int mo = (c & 15) * 8;
        *(bf16x8*)&outp[((size_t)((b * 16 + h) * 64 + d)) * 2048 + lbase + mo] =
            *(const bf16x8*)&smem[d * 144 + mo];
      }
    }
  } else {
    // Q/K: BHLd via LDS bounce (row-major m x 64d, pad 72), b128 stores along d
#pragma unroll
    for (int half = 0; half < 2; half++) {
      __syncthreads();
      if ((wave & 1) == half) {
#pragma unroll
        for (int tm = 0; tm < 4; tm++)
#pragma unroll
          for (int tn = 0; tn < 4; tn++)
#pragma unroll
            for (int r = 0; r < 4; r++) {
              const int ml = wm + tm * 16 + quad * 4 + r;  // 0..127
              const int nl = tn * 16 + l16;                // d 0..63
              smem[ml * 72 + nl] = (short)f2bf((acc[tm][tn][r] + bz[tn]) * sc);
            }
      }
      __syncthreads();
      const int h = (n0 >> 6) + half;
#pragma unroll
      for (int j = 0; j < 4; j++) {
        const int c = tid + j * 256;
        const int ml = c >> 3;          // 0..127
        const int off = (c & 7) * 8;    // 0..56
        *(bf16x8*)&outp[((size_t)(b * 16 + h) * 2048 + lbase + ml) * 64 + off] =
            *(const bf16x8*)&smem[ml * 72 + off];
      }
    }
  }
}

// Output projection: C[8192,1024] fp32 = ctx(bf16) @ WoT^T + bo. g2l16 A+B.
__global__ __launch_bounds__(256, 2) void outproj_k(
    const short* __restrict__ A_g, const short* __restrict__ B_g,
    const float* __restrict__ bias, float* __restrict__ out0) {
  __shared__ short As[4096];
  __shared__ short Bs[4096];

  const int tid = threadIdx.x;
  const int lane = tid & 63;
  const int wave = tid >> 6;
  const int quad = lane >> 4;
  const int l16 = lane & 15;
  const int m0 = blockIdx.x * 128;
  const int n0 = blockIdx.y * 128;
  const int wm = (wave >> 1) * 64;
  const int wn = (wave & 1) * 64;
  const int srow = tid >> 2;
  const int soff = (tid & 3) * 8;

  f32x4 acc[4][4];
#pragma unroll
  for (int i = 0; i < 4; i++)
#pragma unroll
    for (int j = 0; j < 4; j++) acc[i][j] = f32x4{0.f, 0.f, 0.f, 0.f};

  for (int k0 = 0; k0 < 1024; k0 += 32) {
    __syncthreads();
#pragma unroll
    for (int i = 0; i < 2; i++) {
      const int row = srow + i * 64;
      g2l16(&A_g[(size_t)(m0 + row) * 1024 + k0 + soff], &As[row * 32 + soff]);
      g2l16(&B_g[(size_t)(n0 + row) * 1024 + k0 + soff], &Bs[row * 32 + soff]);
    }
    __syncthreads();

    bf16x8 ah[4], bh[4];
#pragma unroll
    for (int t = 0; t < 4; t++) {
      ah[t] = *(const bf16x8*)&As[(wm + t * 16 + l16) * 32 + quad * 8];
      bh[t] = *(const bf16x8*)&Bs[(wn + t * 16 + l16) * 32 + quad * 8];
    }
#pragma unroll
    for (int tm = 0; tm < 4; tm++)
#pragma unroll
      for (int tn = 0; tn < 4; tn++)
        acc[tm][tn] = __builtin_amdgcn_mfma_f32_16x16x32_bf16(ah[tm], bh[tn], acc[tm][tn], 0, 0, 0);
  }

  float bz[4];
#pragma unroll
  for (int tn = 0; tn < 4; tn++) bz[tn] = bias[n0 + wn + tn * 16 + l16];

#pragma unroll
  for (int tm = 0; tm < 4; tm++)
#pragma unroll
    for (int tn = 0; tn < 4; tn++) {
      const int n = n0 + wn + tn * 16 + l16;
#pragma unroll
      for (int r = 0; r < 4; r++) {
        const int m = m0 + wm + tm * 16 + quad * 4 + r;
        out0[(size_t)m * 1024 + n] = acc[tm][tn][r] + bz[tn];
      }
    }
}

// Flash attention, all-plain bf16, no max-tracking. Block = (b,h) x 128 Q rows.
// Grid (bh, qb): XCD = bh%8 -> each (b,h)'s K/V stays in one XCD's L2.
__global__ __launch_bounds__(256, 4) void attn3_k(const short* __restrict__ Qp,
                                                  const short* __restrict__ Kp,
                                                  const short* __restrict__ Vt,
                                                  short* __restrict__ Ctx) {
  __shared__ short Ks[64 * 72];   // [key][d]
  __shared__ short Vs[64 * 72];   // [d][key]
  __shared__ short Ps[128 * 72];  // [qrow][key]

  const int tid = threadIdx.x;
  const int lane = tid & 63;
  const int wave = tid >> 6;
  const int quad = lane >> 4;
  const int l16 = lane & 15;
  const int bh = blockIdx.x;        // XCD-local K/V
  const int q0 = blockIdx.y * 128;

  const short* Kb = Kp + (size_t)bh * 2048 * 64;
  const short* Vb = Vt + (size_t)bh * 64 * 2048;

  bf16x8 qf[2][2];
#pragma unroll
  for (int s = 0; s < 2; s++) {
    const short* qp =
        Qp + ((size_t)bh * 2048 + q0 + wave * 32 + s * 16 + l16) * 64 + quad * 8;
    qf[s][0] = *(const bf16x8*)qp;
    qf[s][1] = *(const bf16x8*)(qp + 32);
  }

  bf16x8 ones;
#pragma unroll
  for (int j = 0; j < 8; j++) ones[j] = (short)0x3F80;

  f32x4 O[2][4], lacc[2];
#pragma unroll
  for (int s = 0; s < 2; s++) {
    lacc[s] = f32x4{0.f, 0.f, 0.f, 0.f};
#pragma unroll
    for (int jo = 0; jo < 4; jo++) O[s][jo] = f32x4{0.f, 0.f, 0.f, 0.f};
  }

  const int srow0 = tid >> 3, soff = (tid & 7) * 8;
  const int srow1 = (tid + 256) >> 3;

  bf16x8 kreg[2], vreg[2];
  kreg[0] = *(const bf16x8*)&Kb[(size_t)srow0 * 64 + soff];
  kreg[1] = *(const bf16x8*)&Kb[(size_t)srow1 * 64 + soff];
  vreg[0] = *(const bf16x8*)&Vb[(size_t)srow0 * 2048 + soff];
  vreg[1] = *(const bf16x8*)&Vb[(size_t)srow1 * 2048 + soff];

  for (int kt = 0; kt < 32; kt++) {
    __syncthreads();
    *(bf16x8*)&Ks[srow0 * 72 + soff] = kreg[0];
    *(bf16x8*)&Ks[srow1 * 72 + soff] = kreg[1];
    *(bf16x8*)&Vs[srow0 * 72 + soff] = vreg[0];
    *(bf16x8*)&Vs[srow1 * 72 + soff] = vreg[1];
    __syncthreads();

    if (kt < 31) {
      const int nb = (kt + 1) * 64;
      kreg[0] = *(const bf16x8*)&Kb[(size_t)(nb + srow0) * 64 + soff];
      kreg[1] = *(const bf16x8*)&Kb[(size_t)(nb + srow1) * 64 + soff];
      vreg[0] = *(const bf16x8*)&Vb[(size_t)srow0 * 2048 + nb + soff];
      vreg[1] = *(const bf16x8*)&Vb[(size_t)srow1 * 2048 + nb + soff];
    }

#pragma unroll
    for (int s = 0; s < 2; s++) {
      f32x4 sacc[4];
#pragma unroll
      for (int j = 0; j < 4; j++) sacc[j] = f32x4{0.f, 0.f, 0.f, 0.f};
#pragma unroll
      for (int c = 0; c < 2; c++)
#pragma unroll
        for (int j = 0; j < 4; j++) {
          const bf16x8 kf = *(const bf16x8*)&Ks[(j * 16 + l16) * 72 + c * 32 + quad * 8];
          sacc[j] = __builtin_amdgcn_mfma_f32_16x16x32_bf16(qf[s][c], kf, sacc[j], 0, 0, 0);
        }
#pragma unroll
      for (int j = 0; j < 4; j++)
#pragma unroll
        for (int r = 0; r < 4; r++) {
          const float e = __expf(sacc[j][r]);
          Ps[(wave * 32 + s * 16 + quad * 4 + r) * 72 + j * 16 + l16] =
              (short)(__float_as_uint(e) >> 16);  // trunc: bias cancels in l
        }
    }
    // no barrier: P readback is wave-local

#pragma unroll
    for (int c = 0; c < 2; c++) {
      const bf16x8 pf0 = *(const bf16x8*)&Ps[(wave * 32 + l16) * 72 + c * 32 + quad * 8];
      const bf16x8 pf1 = *(const bf16x8*)&Ps[(wave * 32 + 16 + l16) * 72 + c * 32 + quad * 8];
      lacc[0] = __builtin_amdgcn_mfma_f32_16x16x32_bf16(pf0, ones, lacc[0], 0, 0, 0);
      lacc[1] = __builtin_amdgcn_mfma_f32_16x16x32_bf16(pf1, ones, lacc[1], 0, 0, 0);
#pragma unroll
      for (int jo = 0; jo < 4; jo++) {
        const bf16x8 vf = *(const bf16x8*)&Vs[(jo * 16 + l16) * 72 + c * 32 + quad * 8];
        O[0][jo] = __builtin_amdgcn_mfma_f32_16x16x32_bf16(pf0, vf, O[0][jo], 0, 0, 0);
        O[1][jo] = __builtin_amdgcn_mfma_f32_16x16x32_bf16(pf1, vf, O[1][jo], 0, 0, 0);
      }
    }
  }

  const int b = bh >> 4, h = bh & 15;
#pragma unroll
  for (int s = 0; s < 2; s++)
#pragma unroll
    for (int r = 0; r < 4; r++) {
      const float inv_l = 1.0f / lacc[s][r];
      const size_t row = (size_t)b * 2048 + q0 + wave * 32 + s * 16 + quad * 4 + r;
#pragma unroll
      for (int jo = 0; jo < 4; jo++)
        Ctx[row * 1024 + h * 64 + jo * 16 + l16] = (short)f2bf(O[s][jo][r] * inv_l);
    }
}

// ===========================================================================
extern "C" void kernel_launch(void* const* d_in, const int* in_sizes, int n_in,
                              void* d_out, int out_size, void* d_ws, size_t ws_size,
                              hipStream_t stream) {
  const float* queries = (const float*)d_in[0];
  const float* keys    = (const float*)d_in[1];
  const float* values  = (const float*)d_in[2];
  const float* Wq = (const float*)d_in[3];
  const float* bq = (const float*)d_in[4];
  const float* Wk = (const float*)d_in[5];
  const float* bk = (const float*)d_in[6];
  const float* Wv = (const float*)d_in[7];
  const float* bv = (const float*)d_in[8];
  const float* Wo = (const float*)d_in[9];
  const float* bo = (const float*)d_in[10];
  float* out = (float*)d_out;

  const size_t PLANE = (size_t)8192 * 1024 * 2;
  const size_t WPL = (size_t)1024 * 1024 * 2;

  char* p = (char*)d_ws;
  short* WT  = (short*)p;  p += 4 * WPL;  // WqT,WkT,WvT,WoT contiguous
  short* Qp  = (short*)p;  p += PLANE;    // Qp,Kp,Vt contiguous (proj3 Obase)
  short* Kp  = (short*)p;  p += PLANE;
  short* Vt  = (short*)p;  p += PLANE;
  short* ctx = (short*)p;  p += PLANE;
  (void)Kp;

  const dim3 blk(256);
  wt4_k<<<dim3(16, 16, 4), blk, 0, stream>>>(Wq, Wk, Wv, Wo, WT);

  proj3_k<<<dim3(64, 8, 3), blk, 0, stream>>>(queries, keys, values, WT,
                                              bq, bk, bv, Qp);

  attn3_k<<<dim3(64, 16), blk, 0, stream>>>(Qp, Kp, Vt, ctx);

  outproj_k<<<dim3(64, 8), blk, 0, stream>>>(ctx, WT + 3 * 1048576, bo, out);
}